// Round 3
// baseline (4297.240 us; speedup 1.0000x reference)
//
#include <hip/hip_runtime.h>
#include <stdint.h>

typedef _Float16 f16x8 __attribute__((ext_vector_type(8)));
typedef float    f32x4 __attribute__((ext_vector_type(4)));

// Problem constants
#define SEQL 1024
#define EMB  1024
#define NH   16
#define HD   64
#define BATCH 8
#define QKVN 3072   // fused QKV output width

// ---------------------------------------------------------------------------
// async global->LDS, 16B per lane
// ---------------------------------------------------------------------------
__device__ __forceinline__ void gll16(const void* g, void* l) {
  __builtin_amdgcn_global_load_lds(
      (const __attribute__((address_space(1))) unsigned int*)(uintptr_t)g,
      (__attribute__((address_space(3))) unsigned int*)(uintptr_t)l, 16, 0, 0);
}

// ---------------------------------------------------------------------------
// prep: fp32->fp16 converts for x, Wq|Wk|Wv (stacked), Wo, bias concat.
// ---------------------------------------------------------------------------
__device__ __forceinline__ void cvt8(const float* __restrict__ in,
                                     _Float16* __restrict__ out, int i) {
  const float4* p = (const float4*)in;
  float4 a = p[2 * i], b = p[2 * i + 1];
  f16x8 o;
  o[0] = (_Float16)a.x; o[1] = (_Float16)a.y; o[2] = (_Float16)a.z; o[3] = (_Float16)a.w;
  o[4] = (_Float16)b.x; o[5] = (_Float16)b.y; o[6] = (_Float16)b.z; o[7] = (_Float16)b.w;
  ((f16x8*)out)[i] = o;
}

__global__ __launch_bounds__(256) void k_prep(const float* __restrict__ x,
                                              const float* __restrict__ Wq,
                                              const float* __restrict__ Wk,
                                              const float* __restrict__ Wv,
                                              const float* __restrict__ Wo,
                                              const float* __restrict__ bq,
                                              const float* __restrict__ bk,
                                              const float* __restrict__ bv,
                                              _Float16* __restrict__ x16,
                                              _Float16* __restrict__ Wqkv16,
                                              _Float16* __restrict__ Wo16,
                                              float* __restrict__ bqkv) {
  const int bid = blockIdx.x, tid = threadIdx.x;
  if (bid < 4096) {
    cvt8(x, x16, bid * 256 + tid);
  } else if (bid < 4608) {
    cvt8(Wq, Wqkv16, (bid - 4096) * 256 + tid);
  } else if (bid < 5120) {
    cvt8(Wk, Wqkv16 + (size_t)EMB * EMB, (bid - 4608) * 256 + tid);
  } else if (bid < 5632) {
    cvt8(Wv, Wqkv16 + (size_t)2 * EMB * EMB, (bid - 5120) * 256 + tid);
  } else if (bid < 6144) {
    cvt8(Wo, Wo16, (bid - 5632) * 256 + tid);
  } else {
    int i = (bid - 6144) * 256 + tid;  // 0..3071
    float v = (i < 1024) ? bq[i] : (i < 2048 ? bk[i - 1024] : bv[i - 2048]);
    bqkv[i] = v;
  }
}

// ---------------------------------------------------------------------------
// NT GEMM: C[M,N] = A[M,K] * B[N,K]^T + bias[N]  (m97-class 128x128, BK=32)
// ---------------------------------------------------------------------------
template <int OUT_F16>
__global__ __launch_bounds__(256) void k_gemm_nt(const _Float16* __restrict__ A,
                                                 const _Float16* __restrict__ B,
                                                 const float* __restrict__ bias,
                                                 void* __restrict__ Cv,
                                                 int M, int N, int K) {
  __shared__ __align__(16) _Float16 As[128 * 32];
  __shared__ __align__(16) _Float16 Bs[128 * 32];
  const int nb = N >> 7;
  const int bm = (int)blockIdx.x / nb, bn = (int)blockIdx.x % nb;
  const int m0 = bm << 7, n0 = bn << 7;
  const int tid = threadIdx.x;
  const int wave = tid >> 6, lane = tid & 63, quad = lane >> 4, l16 = lane & 15;
  const int wm = (wave & 1) << 6, wn = (wave >> 1) << 6;

  f32x4 acc[4][4] = {};

  const int c0 = tid, c1 = tid + 256;
  const int row0 = c0 >> 2, ko0 = (c0 & 3) << 3;
  const int row1 = c1 >> 2, ko1 = (c1 & 3) << 3;
  const _Float16* a0 = A + (size_t)(m0 + row0) * K + ko0;
  const _Float16* a1 = A + (size_t)(m0 + row1) * K + ko1;
  const _Float16* b0 = B + (size_t)(n0 + row0) * K + ko0;
  const _Float16* b1 = B + (size_t)(n0 + row1) * K + ko1;

  for (int k0 = 0; k0 < K; k0 += 32) {
    __syncthreads();
    gll16(a0 + k0, As + (size_t)c0 * 8);
    gll16(a1 + k0, As + (size_t)c1 * 8);
    gll16(b0 + k0, Bs + (size_t)c0 * 8);
    gll16(b1 + k0, Bs + (size_t)c1 * 8);
    __syncthreads();

    f16x8 af[4], bf[4];
#pragma unroll
    for (int i = 0; i < 4; ++i)
      af[i] = *(const f16x8*)(As + ((wm + (i << 4) + l16) << 5) + (quad << 3));
#pragma unroll
    for (int i = 0; i < 4; ++i)
      bf[i] = *(const f16x8*)(Bs + ((wn + (i << 4) + l16) << 5) + (quad << 3));
#pragma unroll
    for (int i = 0; i < 4; ++i)
#pragma unroll
      for (int j = 0; j < 4; ++j)
        acc[i][j] = __builtin_amdgcn_mfma_f32_16x16x32_f16(af[i], bf[j], acc[i][j], 0, 0, 0);
  }

#pragma unroll
  for (int j = 0; j < 4; ++j) {
    int col = n0 + wn + (j << 4) + l16;
    float bb = bias[col];
#pragma unroll
    for (int i = 0; i < 4; ++i) {
      int rowb = m0 + wm + (i << 4) + (quad << 2);
#pragma unroll
      for (int r = 0; r < 4; ++r) {
        float v = acc[i][j][r] + bb;
        if (OUT_F16)
          ((_Float16*)Cv)[(size_t)(rowb + r) * N + col] = (_Float16)v;
        else
          ((float*)Cv)[(size_t)(rowb + r) * N + col] = v;
      }
    }
  }
}

// ---------------------------------------------------------------------------
// V slice of QKV (b, s, 2048 + h*64+d, stride 3072) -> Vt (b, h, d, s) fp16
// ---------------------------------------------------------------------------
__global__ __launch_bounds__(256) void k_transpose_v(const _Float16* __restrict__ QKV,
                                                     _Float16* __restrict__ Vt) {
  int tid = blockIdx.x * 256 + threadIdx.x;  // 2^20 threads
  int d = tid & 63;
  int s0 = ((tid >> 6) & 127) << 3;
  int h = (tid >> 13) & 15;
  int b = tid >> 17;
  const _Float16* src = QKV + ((size_t)(b * SEQL + s0)) * QKVN + 2048 + h * HD + d;
  f16x8 t;
#pragma unroll
  for (int j = 0; j < 8; ++j) t[j] = src[(size_t)j * QKVN];
  *(f16x8*)(Vt + ((size_t)((b * NH + h) * HD + d)) * SEQL + s0) = t;
}

// ---------------------------------------------------------------------------
// Fused scores + softmax + aw-write + PV.  Identical math/structure to r2.
// DIAGNOSTIC this round: body wrapped in a runtime `reps` loop (idempotent —
// each rep recomputes and rewrites the same aw/att values). reps=8 pushes
// this dispatch above the ~360us harness fills so it surfaces in the rocprof
// top-5 WITH its counters; true cost = dur/8.  asm memory clobber at loop
// top prevents cross-rep LICM of global loads (each rep does real work).
// All inter-rep LDS reuse is barrier-protected (kbuf: phase-2+ barriers;
// pob/sm/sl: phase-1 barriers of the next rep).
// ---------------------------------------------------------------------------
#define PPAD2 136  // 128+8 f16: row stride 272B -> 2-way max on P writes
#define OPAD 68    // 64+4 f32

__global__ __launch_bounds__(256, 4) void k_attn_fused(const _Float16* __restrict__ QKV,
                                                       const _Float16* __restrict__ Vt,
                                                       const int* __restrict__ mask,
                                                       float* __restrict__ aw,
                                                       _Float16* __restrict__ att,
                                                       int reps) {
  __shared__ __align__(16) _Float16 kbuf[8192];      // 16 KB: K chunk [128][64] swizzled
  __shared__ __align__(16) char pob[4][4352];        // 17 KB: P (fp16) then O (fp32)
  __shared__ float sm[4][16], sl[4][16];             // 512 B

  const int qt = blockIdx.x, h = blockIdx.y, b = blockIdx.z;
  const int tid = threadIdx.x;
  const int wave = tid >> 6, lane = tid & 63, quad = lane >> 4, l16 = lane & 15;

  // loop-invariant address setup
  const _Float16* Qbase =
      QKV + ((size_t)(b * SEQL + qt * 16 + l16)) * QKVN + h * HD + quad * 8;
  const int* mrow = mask + b * SEQL;
  const _Float16* Kg = QKV + (size_t)b * SEQL * QKVN + 1024 + h * HD;
  const int krow = tid >> 3;                    // 0..31 per issue-group
  const int kdch = (tid & 7) ^ (krow & 7);
  const _Float16* Kme = Kg + (size_t)krow * QKVN + kdch * 8;
  _Float16* kdst = kbuf + (size_t)tid * 8;
  float* awb = aw + (((size_t)(b * NH + h)) * SEQL + qt * 16) * SEQL;
  const _Float16* vtb = Vt + ((size_t)(b * NH + h)) * HD * SEQL;

  for (int rep = 0; rep < reps; ++rep) {
    asm volatile("" ::: "memory");  // defeat cross-rep LICM of global loads

    // ---- Q fragment (16 rows x 64d, in registers) -------------------------
    f16x8 qf0 = *(const f16x8*)(Qbase);
    f16x8 qf1 = *(const f16x8*)(Qbase + 32);

    float p[16][4];
    float mr[4], lr[4];
#pragma unroll
    for (int r = 0; r < 4; ++r) mr[r] = -3.0e38f;

    // ---- phase 1: scores via LDS-staged K chunks (8 x 128 rows) -----------
    for (int c = 0; c < 8; ++c) {
      if (c | rep) __syncthreads();  // all waves done reading previous chunk
#pragma unroll
      for (int g = 0; g < 4; ++g)
        gll16(Kme + (size_t)(c * 128 + g * 32) * QKVN, kdst + (size_t)g * 2048);
      __syncthreads();         // staged (barrier drains vmcnt)
#pragma unroll
      for (int ctw = 0; ctw < 2; ++ctw) {
        int sloc = wave * 32 + ctw * 16 + l16;          // row within chunk
        int ch0 = sloc * 8 + (quad ^ (sloc & 7));       // swizzled 16B-chunk (d=quad*8)
        f16x8 kf0 = *(const f16x8*)(kbuf + (size_t)ch0 * 8);
        f16x8 kf1 = *(const f16x8*)(kbuf + (size_t)(ch0 ^ 4) * 8);  // d=32+quad*8
        f32x4 acc = {};
        acc = __builtin_amdgcn_mfma_f32_16x16x32_f16(qf0, kf0, acc, 0, 0, 0);
        acc = __builtin_amdgcn_mfma_f32_16x16x32_f16(qf1, kf1, acc, 0, 0, 0);
        int col = c * 128 + sloc;
        bool mk = (mrow[col] == 0);
        int pidx = c * 2 + ctw;
#pragma unroll
        for (int r = 0; r < 4; ++r) {
          float s = acc[r] * 0.125f;          // 1/sqrt(64)
          s = fminf(fmaxf(s, -50.f), 50.f);   // clip BEFORE mask (matches ref)
          if (mk) s = -1.0e9f;
          p[pidx][r] = s;
          mr[r] = fmaxf(mr[r], s);
        }
      }
    }

    // ---- phase 2: softmax stats -------------------------------------------
#pragma unroll
    for (int r = 0; r < 4; ++r) {
      float m = mr[r];
      m = fmaxf(m, __shfl_xor(m, 1, 16));
      m = fmaxf(m, __shfl_xor(m, 2, 16));
      m = fmaxf(m, __shfl_xor(m, 4, 16));
      m = fmaxf(m, __shfl_xor(m, 8, 16));
      mr[r] = m;
    }
#pragma unroll
    for (int r = 0; r < 4; ++r) lr[r] = 0.f;
#pragma unroll
    for (int pidx = 0; pidx < 16; ++pidx) {
#pragma unroll
      for (int r = 0; r < 4; ++r) {
        float e = __expf(p[pidx][r] - mr[r]);
        p[pidx][r] = e;
        lr[r] += e;
      }
    }
#pragma unroll
    for (int r = 0; r < 4; ++r) {
      float l = lr[r];
      l += __shfl_xor(l, 1, 16);
      l += __shfl_xor(l, 2, 16);
      l += __shfl_xor(l, 4, 16);
      l += __shfl_xor(l, 8, 16);
      lr[r] = l;
    }
    if (l16 == 0) {
#pragma unroll
      for (int r = 0; r < 4; ++r) {
        sm[wave][quad * 4 + r] = mr[r];
        sl[wave][quad * 4 + r] = lr[r];
      }
    }
    __syncthreads();  // sm/sl visible; also: all phase-1 kbuf reads done

    float f[4];
#pragma unroll
    for (int r = 0; r < 4; ++r) {
      int row = quad * 4 + r;
      float M = fmaxf(fmaxf(sm[0][row], sm[1][row]), fmaxf(sm[2][row], sm[3][row]));
      float L = sl[0][row] * __expf(sm[0][row] - M) + sl[1][row] * __expf(sm[1][row] - M) +
                sl[2][row] * __expf(sm[2][row] - M) + sl[3][row] * __expf(sm[3][row] - M);
      f[r] = __expf(mr[r] - M) / L;
    }

    // ---- phase 3+4: per k-half {write aw+P, PV} ---------------------------
    _Float16* pw = (_Float16*)pob[wave];
    f32x4 opv[4] = {};
#pragma unroll
    for (int hf = 0; hf < 2; ++hf) {
#pragma unroll
      for (int pl = 0; pl < 8; ++pl) {
        int pidx = hf * 8 + pl;
        int col = ((pidx >> 1) << 7) + (wave << 5) + ((pidx & 1) << 4) + l16;
#pragma unroll
        for (int r = 0; r < 4; ++r) {
          float v = p[pidx][r] * f[r];
          awb[(size_t)(quad * 4 + r) * SEQL + col] = v;
          pw[(quad * 4 + r) * PPAD2 + pl * 16 + l16] = (_Float16)v;
        }
      }
      // PV over this half's 4 k-steps; V read direct (L2-resident).
#pragma unroll
      for (int j = 0; j < 4; ++j) {
        f16x8 af = *(const f16x8*)(pw + l16 * PPAD2 + j * 32 + quad * 8);
        int sbase = ((hf * 4 + j) << 7) + (wave << 5) + (quad << 3);
#pragma unroll
        for (int nt = 0; nt < 4; ++nt) {
          f16x8 bf = *(const f16x8*)(vtb + (size_t)(nt * 16 + l16) * SEQL + sbase);
          opv[nt] = __builtin_amdgcn_mfma_f32_16x16x32_f16(af, bf, opv[nt], 0, 0, 0);
        }
      }
    }

    // ---- phase 5: cross-wave O reduction + att write ----------------------
    float* ob = (float*)&pob[0][0];  // [4][16*OPAD] == 4 x 4352 B
#pragma unroll
    for (int nt = 0; nt < 4; ++nt)
#pragma unroll
      for (int r = 0; r < 4; ++r)
        ob[(wave * 16 + quad * 4 + r) * OPAD + nt * 16 + l16] = opv[nt][r];
    __syncthreads();

    {
      int col = tid & 63;
      int r0 = tid >> 6;
#pragma unroll
      for (int i = 0; i < 4; ++i) {
        int row = r0 + i * 4;
        float o = ob[row * OPAD + col] + ob[(16 + row) * OPAD + col] +
                  ob[(32 + row) * OPAD + col] + ob[(48 + row) * OPAD + col];
        att[((size_t)(b * SEQL + qt * 16 + row)) * EMB + h * HD + col] = (_Float16)o;
      }
    }
  }
}

// ---------------------------------------------------------------------------
// launch
// ---------------------------------------------------------------------------
extern "C" void kernel_launch(void* const* d_in, const int* in_sizes, int n_in,
                              void* d_out, int out_size, void* d_ws, size_t ws_size,
                              hipStream_t stream) {
  const float* x  = (const float*)d_in[0];
  const int* mask = (const int*)d_in[1];
  const float* Wq = (const float*)d_in[2];
  const float* bq = (const float*)d_in[3];
  const float* Wk = (const float*)d_in[4];
  const float* bk = (const float*)d_in[5];
  const float* Wv = (const float*)d_in[6];
  const float* bv = (const float*)d_in[7];
  const float* Wo = (const float*)d_in[8];
  const float* bo = (const float*)d_in[9];

  float* out = (float*)d_out;
  float* aw = out + (size_t)BATCH * SEQL * EMB;  // 8,388,608 floats in

  char* ws = (char*)d_ws;
  _Float16* x16    = (_Float16*)(ws);                        // 16 MB
  _Float16* Wqkv16 = (_Float16*)(ws + ((size_t)16 << 20));   // 6 MB
  _Float16* Wo16   = (_Float16*)(ws + ((size_t)22 << 20));   // 2 MB
  float*    bqkv   = (float*)   (ws + ((size_t)24 << 20));   // 12 KB
  _Float16* QKV16  = (_Float16*)(ws + ((size_t)25 << 20));   // 48 MB
  _Float16* Vt16   = (_Float16*)(ws + ((size_t)73 << 20));   // 16 MB
  _Float16* att16  = (_Float16*)(ws + ((size_t)89 << 20));   // 16 MB (total 105 MB)

  const int M = BATCH * SEQL;

  k_prep<<<6156, 256, 0, stream>>>(x, Wq, Wk, Wv, Wo, bq, bk, bv,
                                   x16, Wqkv16, Wo16, bqkv);

  k_gemm_nt<1><<<(M / 128) * (QKVN / 128), 256, 0, stream>>>(x16, Wqkv16, bqkv, QKV16,
                                                             M, QKVN, EMB);

  k_transpose_v<<<4096, 256, 0, stream>>>(QKV16, Vt16);

  // DIAGNOSTIC: reps=8 — surfaces k_attn_fused in rocprof top-5 (true cost = dur/8)
  k_attn_fused<<<dim3(SEQL / 16, NH, BATCH), 256, 0, stream>>>(QKV16, Vt16, mask, aw, att16, 8);

  k_gemm_nt<0><<<(M / 128) * (EMB / 128), 256, 0, stream>>>(att16, Wo16, bo, out,
                                                            M, EMB, EMB);
}

// Round 4
// 868.450 us; speedup vs baseline: 4.9482x; 4.9482x over previous
//
#include <hip/hip_runtime.h>
#include <stdint.h>

typedef _Float16 f16x8 __attribute__((ext_vector_type(8)));
typedef float    f32x4 __attribute__((ext_vector_type(4)));

// Problem constants
#define SEQL 1024
#define EMB  1024
#define NH   16
#define HD   64
#define BATCH 8
#define QKVN 3072   // fused QKV output width

// ---------------------------------------------------------------------------
// async global->LDS, 16B per lane
// ---------------------------------------------------------------------------
__device__ __forceinline__ void gll16(const void* g, void* l) {
  __builtin_amdgcn_global_load_lds(
      (const __attribute__((address_space(1))) unsigned int*)(uintptr_t)g,
      (__attribute__((address_space(3))) unsigned int*)(uintptr_t)l, 16, 0, 0);
}

// ---------------------------------------------------------------------------
// prep: fp32->fp16 converts for x, Wq|Wk|Wv (stacked), Wo, bias concat.
// ---------------------------------------------------------------------------
__device__ __forceinline__ void cvt8(const float* __restrict__ in,
                                     _Float16* __restrict__ out, int i) {
  const float4* p = (const float4*)in;
  float4 a = p[2 * i], b = p[2 * i + 1];
  f16x8 o;
  o[0] = (_Float16)a.x; o[1] = (_Float16)a.y; o[2] = (_Float16)a.z; o[3] = (_Float16)a.w;
  o[4] = (_Float16)b.x; o[5] = (_Float16)b.y; o[6] = (_Float16)b.z; o[7] = (_Float16)b.w;
  ((f16x8*)out)[i] = o;
}

__global__ __launch_bounds__(256) void k_prep(const float* __restrict__ x,
                                              const float* __restrict__ Wq,
                                              const float* __restrict__ Wk,
                                              const float* __restrict__ Wv,
                                              const float* __restrict__ Wo,
                                              const float* __restrict__ bq,
                                              const float* __restrict__ bk,
                                              const float* __restrict__ bv,
                                              _Float16* __restrict__ x16,
                                              _Float16* __restrict__ Wqkv16,
                                              _Float16* __restrict__ Wo16,
                                              float* __restrict__ bqkv) {
  const int bid = blockIdx.x, tid = threadIdx.x;
  if (bid < 4096) {
    cvt8(x, x16, bid * 256 + tid);
  } else if (bid < 4608) {
    cvt8(Wq, Wqkv16, (bid - 4096) * 256 + tid);
  } else if (bid < 5120) {
    cvt8(Wk, Wqkv16 + (size_t)EMB * EMB, (bid - 4608) * 256 + tid);
  } else if (bid < 5632) {
    cvt8(Wv, Wqkv16 + (size_t)2 * EMB * EMB, (bid - 5120) * 256 + tid);
  } else if (bid < 6144) {
    cvt8(Wo, Wo16, (bid - 5632) * 256 + tid);
  } else {
    int i = (bid - 6144) * 256 + tid;  // 0..3071
    float v = (i < 1024) ? bq[i] : (i < 2048 ? bk[i - 1024] : bv[i - 2048]);
    bqkv[i] = v;
  }
}

// ---------------------------------------------------------------------------
// NT GEMM: C[M,N] = A[M,K] * B[N,K]^T + bias[N]  (m97-class 128x128, BK=32)
// ---------------------------------------------------------------------------
template <int OUT_F16>
__global__ __launch_bounds__(256) void k_gemm_nt(const _Float16* __restrict__ A,
                                                 const _Float16* __restrict__ B,
                                                 const float* __restrict__ bias,
                                                 void* __restrict__ Cv,
                                                 int M, int N, int K) {
  __shared__ __align__(16) _Float16 As[128 * 32];
  __shared__ __align__(16) _Float16 Bs[128 * 32];
  const int nb = N >> 7;
  const int bm = (int)blockIdx.x / nb, bn = (int)blockIdx.x % nb;
  const int m0 = bm << 7, n0 = bn << 7;
  const int tid = threadIdx.x;
  const int wave = tid >> 6, lane = tid & 63, quad = lane >> 4, l16 = lane & 15;
  const int wm = (wave & 1) << 6, wn = (wave >> 1) << 6;

  f32x4 acc[4][4] = {};

  const int c0 = tid, c1 = tid + 256;
  const int row0 = c0 >> 2, ko0 = (c0 & 3) << 3;
  const int row1 = c1 >> 2, ko1 = (c1 & 3) << 3;
  const _Float16* a0 = A + (size_t)(m0 + row0) * K + ko0;
  const _Float16* a1 = A + (size_t)(m0 + row1) * K + ko1;
  const _Float16* b0 = B + (size_t)(n0 + row0) * K + ko0;
  const _Float16* b1 = B + (size_t)(n0 + row1) * K + ko1;

  for (int k0 = 0; k0 < K; k0 += 32) {
    __syncthreads();
    gll16(a0 + k0, As + (size_t)c0 * 8);
    gll16(a1 + k0, As + (size_t)c1 * 8);
    gll16(b0 + k0, Bs + (size_t)c0 * 8);
    gll16(b1 + k0, Bs + (size_t)c1 * 8);
    __syncthreads();

    f16x8 af[4], bf[4];
#pragma unroll
    for (int i = 0; i < 4; ++i)
      af[i] = *(const f16x8*)(As + ((wm + (i << 4) + l16) << 5) + (quad << 3));
#pragma unroll
    for (int i = 0; i < 4; ++i)
      bf[i] = *(const f16x8*)(Bs + ((wn + (i << 4) + l16) << 5) + (quad << 3));
#pragma unroll
    for (int i = 0; i < 4; ++i)
#pragma unroll
      for (int j = 0; j < 4; ++j)
        acc[i][j] = __builtin_amdgcn_mfma_f32_16x16x32_f16(af[i], bf[j], acc[i][j], 0, 0, 0);
  }

#pragma unroll
  for (int j = 0; j < 4; ++j) {
    int col = n0 + wn + (j << 4) + l16;
    float bb = bias[col];
#pragma unroll
    for (int i = 0; i < 4; ++i) {
      int rowb = m0 + wm + (i << 4) + (quad << 2);
#pragma unroll
      for (int r = 0; r < 4; ++r) {
        float v = acc[i][j][r] + bb;
        if (OUT_F16)
          ((_Float16*)Cv)[(size_t)(rowb + r) * N + col] = (_Float16)v;
        else
          ((float*)Cv)[(size_t)(rowb + r) * N + col] = v;
      }
    }
  }
}

// ---------------------------------------------------------------------------
// V slice of QKV (b, s, 2048 + h*64+d, stride 3072) -> Vt (b, h, d, s) fp16
// ---------------------------------------------------------------------------
__global__ __launch_bounds__(256) void k_transpose_v(const _Float16* __restrict__ QKV,
                                                     _Float16* __restrict__ Vt) {
  int tid = blockIdx.x * 256 + threadIdx.x;  // 2^20 threads
  int d = tid & 63;
  int s0 = ((tid >> 6) & 127) << 3;
  int h = (tid >> 13) & 15;
  int b = tid >> 17;
  const _Float16* src = QKV + ((size_t)(b * SEQL + s0)) * QKVN + 2048 + h * HD + d;
  f16x8 t;
#pragma unroll
  for (int j = 0; j < 8; ++j) t[j] = src[(size_t)j * QKVN];
  *(f16x8*)(Vt + ((size_t)((b * NH + h) * HD + d)) * SEQL + s0) = t;
}

// ---------------------------------------------------------------------------
// Fused scores + softmax + aw-write + PV.  v4 (counter-driven, from r2 probe:
// t_attn=490us, 1.7GB HBM/launch vs 0.58GB mandatory, occ 41%, all pipes idle):
//  1) XCD swizzle: 1D grid, swz=(wg&7)*1024+(wg>>3) -> each XCD runs whole
//     (b,h) panels -> K/V slices XCD-L2-resident (K/V HBM fetch ~8x down).
//  2) aw stores non-temporal (streaming): kills the ~500MB read-for-ownership
//     fetch on the 512MB aw output and stops aw thrashing L2.
//  3) K read DIRECT from global (L2-resident now; staging was proven
//     cost-neutral in r0): phase 1 loses all 16 barriers; LDS 34.3->17.9KB;
//     with VGPR=64 -> 8 blocks/CU (was 3.3).  2 barriers/block total.
// ---------------------------------------------------------------------------
#define PPAD2 136  // 128+8 f16: row stride 272B -> 2-way max on P writes
#define OPAD 68    // 64+4 f32

__global__ __launch_bounds__(256, 4) void k_attn_fused(const _Float16* __restrict__ QKV,
                                                       const _Float16* __restrict__ Vt,
                                                       const int* __restrict__ mask,
                                                       float* __restrict__ aw,
                                                       _Float16* __restrict__ att) {
  __shared__ __align__(16) char pob[4][4352];        // 17 KB: P (fp16) then O (fp32)
  __shared__ float sm[4][16], sl[4][16];             // 512 B

  // XCD-aware decode: consecutive dispatch ids round-robin XCDs; this swizzle
  // gives each XCD a contiguous run of qt for fixed (b,h).
  const int wg = (int)blockIdx.x;                    // 0..8191
  const int swz = ((wg & 7) << 10) | (wg >> 3);
  const int qt = swz & 63, h = (swz >> 6) & 15, b = swz >> 10;

  const int tid = threadIdx.x;
  const int wave = tid >> 6, lane = tid & 63, quad = lane >> 4, l16 = lane & 15;

  // ---- Q fragment (16 rows x 64d, in registers) ---------------------------
  const _Float16* Qbase =
      QKV + ((size_t)(b * SEQL + qt * 16 + l16)) * QKVN + h * HD + quad * 8;
  f16x8 qf0 = *(const f16x8*)(Qbase);
  f16x8 qf1 = *(const f16x8*)(Qbase + 32);

  float p[16][4];
  float mr[4], lr[4];
#pragma unroll
  for (int r = 0; r < 4; ++r) mr[r] = -3.0e38f;

  const int* mrow = mask + b * SEQL;

  // ---- phase 1: scores, K direct from global (XCD-L2-resident) ------------
  // wave owns contiguous cols wave*256 + ct*16 + l16 (ct = 0..15 = pidx).
  const _Float16* Kb0 = QKV + (size_t)b * SEQL * QKVN + 1024 + h * HD + quad * 8;
#pragma unroll
  for (int ct = 0; ct < 16; ++ct) {
    int col = (wave << 8) + (ct << 4) + l16;
    const _Float16* Kb = Kb0 + (size_t)col * QKVN;
    f16x8 kf0 = *(const f16x8*)(Kb);
    f16x8 kf1 = *(const f16x8*)(Kb + 32);
    f32x4 acc = {};
    acc = __builtin_amdgcn_mfma_f32_16x16x32_f16(qf0, kf0, acc, 0, 0, 0);
    acc = __builtin_amdgcn_mfma_f32_16x16x32_f16(qf1, kf1, acc, 0, 0, 0);
    bool mk = (mrow[col] == 0);
#pragma unroll
    for (int r = 0; r < 4; ++r) {
      float s = acc[r] * 0.125f;          // 1/sqrt(64)
      s = fminf(fmaxf(s, -50.f), 50.f);   // clip BEFORE mask (matches ref)
      if (mk) s = -1.0e9f;
      p[ct][r] = s;
      mr[r] = fmaxf(mr[r], s);
    }
  }

  // ---- phase 2: softmax stats ---------------------------------------------
#pragma unroll
  for (int r = 0; r < 4; ++r) {
    float m = mr[r];
    m = fmaxf(m, __shfl_xor(m, 1, 16));
    m = fmaxf(m, __shfl_xor(m, 2, 16));
    m = fmaxf(m, __shfl_xor(m, 4, 16));
    m = fmaxf(m, __shfl_xor(m, 8, 16));
    mr[r] = m;
  }
#pragma unroll
  for (int r = 0; r < 4; ++r) lr[r] = 0.f;
#pragma unroll
  for (int pidx = 0; pidx < 16; ++pidx) {
#pragma unroll
    for (int r = 0; r < 4; ++r) {
      float e = __expf(p[pidx][r] - mr[r]);
      p[pidx][r] = e;
      lr[r] += e;
    }
  }
#pragma unroll
  for (int r = 0; r < 4; ++r) {
    float l = lr[r];
    l += __shfl_xor(l, 1, 16);
    l += __shfl_xor(l, 2, 16);
    l += __shfl_xor(l, 4, 16);
    l += __shfl_xor(l, 8, 16);
    lr[r] = l;
  }
  if (l16 == 0) {
#pragma unroll
    for (int r = 0; r < 4; ++r) {
      sm[wave][quad * 4 + r] = mr[r];
      sl[wave][quad * 4 + r] = lr[r];
    }
  }
  __syncthreads();  // sm/sl visible  (barrier 1 of 2)

  float f[4];
#pragma unroll
  for (int r = 0; r < 4; ++r) {
    int row = quad * 4 + r;
    float M = fmaxf(fmaxf(sm[0][row], sm[1][row]), fmaxf(sm[2][row], sm[3][row]));
    float L = sl[0][row] * __expf(sm[0][row] - M) + sl[1][row] * __expf(sm[1][row] - M) +
              sl[2][row] * __expf(sm[2][row] - M) + sl[3][row] * __expf(sm[3][row] - M);
    f[r] = __expf(mr[r] - M) / L;
  }

  // ---- phase 3+4: per k-half {write aw (nt) + P, PV} ----------------------
  // pbuf is wave-private -> ds_write->ds_read ordering is in-wave, no barriers.
  float* awb = aw + (((size_t)(b * NH + h)) * SEQL + qt * 16) * SEQL;
  _Float16* pw = (_Float16*)pob[wave];
  const _Float16* vtb = Vt + ((size_t)(b * NH + h)) * HD * SEQL;
  f32x4 opv[4] = {};
#pragma unroll
  for (int hf = 0; hf < 2; ++hf) {
#pragma unroll
    for (int pl = 0; pl < 8; ++pl) {
      int pidx = hf * 8 + pl;
      int col = (wave << 8) + (pidx << 4) + l16;   // matches phase-1 ownership
#pragma unroll
      for (int r = 0; r < 4; ++r) {
        float v = p[pidx][r] * f[r];
        __builtin_nontemporal_store(v, &awb[(size_t)(quad * 4 + r) * SEQL + col]);
        pw[(quad * 4 + r) * PPAD2 + pl * 16 + l16] = (_Float16)v;
      }
    }
    // PV over this half's 4 k-steps; V direct (XCD-L2-resident).
    // local k = j*32 + quad*8 + jj  <->  s = wave*256 + hf*128 + j*32 + quad*8 + jj
#pragma unroll
    for (int j = 0; j < 4; ++j) {
      f16x8 af = *(const f16x8*)(pw + l16 * PPAD2 + j * 32 + quad * 8);
      int sbase = (wave << 8) + (hf << 7) + (j << 5) + (quad << 3);
#pragma unroll
      for (int nt = 0; nt < 4; ++nt) {
        f16x8 bf = *(const f16x8*)(vtb + (size_t)(nt * 16 + l16) * SEQL + sbase);
        opv[nt] = __builtin_amdgcn_mfma_f32_16x16x32_f16(af, bf, opv[nt], 0, 0, 0);
      }
    }
  }

  // ---- phase 5: cross-wave O reduction + att write ------------------------
  // O aliases P: wave w's O rows land exactly in pob[w] (own region; in-wave
  // ordering protects its dead P data).  One barrier, then reduce.
  float* ob = (float*)&pob[0][0];  // [4][16*OPAD] == 4 x 4352 B
#pragma unroll
  for (int nt = 0; nt < 4; ++nt)
#pragma unroll
    for (int r = 0; r < 4; ++r)
      ob[(wave * 16 + quad * 4 + r) * OPAD + nt * 16 + l16] = opv[nt][r];
  __syncthreads();  // (barrier 2 of 2)

  {
    int col = tid & 63;
    int r0 = tid >> 6;
#pragma unroll
    for (int i = 0; i < 4; ++i) {
      int row = r0 + i * 4;
      float o = ob[row * OPAD + col] + ob[(16 + row) * OPAD + col] +
                ob[(32 + row) * OPAD + col] + ob[(48 + row) * OPAD + col];
      att[((size_t)(b * SEQL + qt * 16 + row)) * EMB + h * HD + col] = (_Float16)o;
    }
  }
}

// ---------------------------------------------------------------------------
// launch
// ---------------------------------------------------------------------------
extern "C" void kernel_launch(void* const* d_in, const int* in_sizes, int n_in,
                              void* d_out, int out_size, void* d_ws, size_t ws_size,
                              hipStream_t stream) {
  const float* x  = (const float*)d_in[0];
  const int* mask = (const int*)d_in[1];
  const float* Wq = (const float*)d_in[2];
  const float* bq = (const float*)d_in[3];
  const float* Wk = (const float*)d_in[4];
  const float* bk = (const float*)d_in[5];
  const float* Wv = (const float*)d_in[6];
  const float* bv = (const float*)d_in[7];
  const float* Wo = (const float*)d_in[8];
  const float* bo = (const float*)d_in[9];

  float* out = (float*)d_out;
  float* aw = out + (size_t)BATCH * SEQL * EMB;  // 8,388,608 floats in

  char* ws = (char*)d_ws;
  _Float16* x16    = (_Float16*)(ws);                        // 16 MB
  _Float16* Wqkv16 = (_Float16*)(ws + ((size_t)16 << 20));   // 6 MB
  _Float16* Wo16   = (_Float16*)(ws + ((size_t)22 << 20));   // 2 MB
  float*    bqkv   = (float*)   (ws + ((size_t)24 << 20));   // 12 KB
  _Float16* QKV16  = (_Float16*)(ws + ((size_t)25 << 20));   // 48 MB
  _Float16* Vt16   = (_Float16*)(ws + ((size_t)73 << 20));   // 16 MB
  _Float16* att16  = (_Float16*)(ws + ((size_t)89 << 20));   // 16 MB (total 105 MB)

  const int M = BATCH * SEQL;

  k_prep<<<6156, 256, 0, stream>>>(x, Wq, Wk, Wv, Wo, bq, bk, bv,
                                   x16, Wqkv16, Wo16, bqkv);

  k_gemm_nt<1><<<(M / 128) * (QKVN / 128), 256, 0, stream>>>(x16, Wqkv16, bqkv, QKV16,
                                                             M, QKVN, EMB);

  k_transpose_v<<<4096, 256, 0, stream>>>(QKV16, Vt16);

  k_attn_fused<<<SEQL / 16 * NH * BATCH, 256, 0, stream>>>(QKV16, Vt16, mask, aw, att16);

  k_gemm_nt<0><<<(M / 128) * (EMB / 128), 256, 0, stream>>>(att16, Wo16, bo, out,
                                                            M, EMB, EMB);
}